// Round 6
// baseline (422.132 us; speedup 1.0000x reference)
//
#include <hip/hip_runtime.h>
#include <hip/hip_bf16.h>
#include <cstdint>

#define DD 8192
#define NROW 200
#define MT 13          // 13 M-tiles of 16 rows = 208
#define MPAD 208
#define KPV 256        // padded K for the PV GEMM
#define EPSV 1e-5f
#define BK 64
#define ABUF_BYTES (MPAD * BK * 2)   // 26624 bytes per LDS A-buffer

using short8 = __attribute__((ext_vector_type(8))) short;
using f32x4  = __attribute__((ext_vector_type(4))) float;

#define MEMBAR asm volatile("" ::: "memory")

__device__ __forceinline__ ushort f2bf(float f) {
    union { float f; unsigned u; } c; c.f = f;
    unsigned u = c.u;
    return (ushort)((u + 0x7FFFu + ((u >> 16) & 1u)) >> 16);  // RNE
}

__device__ __forceinline__ short8 pack8(float4 a, float4 b) {
    short8 o;
    o[0]=f2bf(a.x); o[1]=f2bf(a.y); o[2]=f2bf(a.z); o[3]=f2bf(a.w);
    o[4]=f2bf(b.x); o[5]=f2bf(b.y); o[6]=f2bf(b.z); o[7]=f2bf(b.w);
    return o;
}

// ---------------- kernel 1: x (f32 [200][8192]) -> xb (bf16 [208][8192], pad rows 0)
__global__ void cvt_x(const float* __restrict__ x, ushort* __restrict__ xb) {
    int i = (blockIdx.x * 256 + threadIdx.x) * 8;
    int row = i >> 13;
    int col = i & (DD - 1);
    short8 o;
    if (row < NROW) {
        const float4* p = reinterpret_cast<const float4*>(x + (size_t)row * DD + col);
        float4 a = p[0], b = p[1];
        o = pack8(a, b);
    } else {
        for (int j = 0; j < 8; ++j) o[j] = 0;
    }
    *reinterpret_cast<short8*>(xb + i) = o;
}

// ---------------- kernel 2: fused QKV GEMM with K-split.
// grid (64, 3, KS), block 256 (4 waves). Block: 128 N-cols (wave: 2 colgroups = 32),
// K-chunk = 8192/KS. A k-slice [208][64] bf16 dbuf in LDS (gl_lds, swizzled source,
// 2-barrier counted-vmcnt phases); W regs 1 phase ahead. 3 blocks/CU, 12 waves/CU.
// KS>1: writes fp32 partials [mat][ks][208][8192]. KS==1: direct bf16 epilogue.
__global__ __launch_bounds__(256, 3) void qkv_gemm(
    const ushort* __restrict__ xb,
    const float* __restrict__ Wq, const float* __restrict__ Wk, const float* __restrict__ Wv,
    const float* __restrict__ bq, const float* __restrict__ bk, const float* __restrict__ bv,
    ushort* __restrict__ qb, ushort* __restrict__ kb, ushort* __restrict__ vt,
    float* __restrict__ part, int kchunk)
{
    __shared__ char Asm[2 * ABUF_BYTES];   // 53,248 B -> 3 blocks/CU

    const int mat = blockIdx.y;
    const float* W    = (mat == 0) ? Wq : (mat == 1 ? Wk : Wv);
    const float* bias = (mat == 0) ? bq : (mat == 1 ? bk : bv);

    const int t     = threadIdx.x;
    const int lane  = t & 63;
    const int wave  = t >> 6;
    const int col16 = lane & 15;
    const int kgrp  = lane >> 4;
    const int ncol0 = blockIdx.x * 128 + wave * 32 + col16;
    const int ncol1 = ncol0 + 16;
    const int kbase = blockIdx.z * kchunk;
    const int kmask = kchunk - 1;

    const float* wp0 = W + (size_t)ncol0 * DD + kgrp * 8;
    const float* wp1 = W + (size_t)ncol1 * DD + kgrp * 8;

    // Staging: each gl_lds = 64 lanes x 16B = 1KB = 8 rows x 128B (linear LDS).
    // Swizzled content at (row, slot16B): k-chunk = slot ^ (row&7).
    // lane l: row_local = l>>3, slot = l&7 -> src k-chunk = (l&7) ^ ((l>>3)&7).
    const ushort* sbase = xb + (size_t)(lane >> 3) * DD
                             + (size_t)(((lane & 7) ^ ((lane >> 3) & 7)) * 8);
    // 26 gl_lds per 208-row slice; wave w stages rows r0w..r0w+sw-1 (7/7/6/6)
    const int r0w = (wave < 2) ? wave * 7 : 14 + (wave - 2) * 6;
    const int sw  = (wave < 2) ? 7 : 6;

    // ds_read: a-frag (m, chunk c): row = m*16+col16, slot = (c(=kgrp or kgrp+4)) ^ (col16&7)
    const int b0off = col16 * 128 + ((kgrp ^ (col16 & 7)) * 16);
    const int b1off = b0off ^ 64;

    f32x4 acc0[MT], acc1[MT];
    #pragma unroll
    for (int m = 0; m < MT; ++m)
        for (int r = 0; r < 4; ++r) { acc0[m][r] = 0.f; acc1[m][r] = 0.f; }

#define STAGE(BOFF, KK) { _Pragma("unroll") for (int rr = 0; rr < 7; ++rr) { if (rr < sw) { \
        __builtin_amdgcn_global_load_lds( \
            (const __attribute__((address_space(1))) void*)(sbase + (KK) + (size_t)(r0w + rr) * 8 * DD), \
            (__attribute__((address_space(3))) void*)(Asm + (BOFF) + (r0w + rr) * 1024), \
            16, 0, 0); } } }

#define LOADW(d, KK) { \
        d##0 = *reinterpret_cast<const float4*>(wp0 + (KK)); \
        d##1 = *reinterpret_cast<const float4*>(wp0 + (KK) + 4); \
        d##2 = *reinterpret_cast<const float4*>(wp0 + (KK) + 32); \
        d##3 = *reinterpret_cast<const float4*>(wp0 + (KK) + 36); \
        d##4 = *reinterpret_cast<const float4*>(wp1 + (KK)); \
        d##5 = *reinterpret_cast<const float4*>(wp1 + (KK) + 4); \
        d##6 = *reinterpret_cast<const float4*>(wp1 + (KK) + 32); \
        d##7 = *reinterpret_cast<const float4*>(wp1 + (KK) + 36); }

#define COMPUTE(BASE, b00, b01, b10, b11) { \
        _Pragma("unroll") for (int m = 0; m < MT; ++m) { \
            short8 a0 = *reinterpret_cast<const short8*>(Asm + (BASE) + b0off + m * 2048); \
            acc0[m] = __builtin_amdgcn_mfma_f32_16x16x32_bf16(a0, b00, acc0[m], 0, 0, 0); \
            acc1[m] = __builtin_amdgcn_mfma_f32_16x16x32_bf16(a0, b10, acc1[m], 0, 0, 0); \
            short8 a1 = *reinterpret_cast<const short8*>(Asm + (BASE) + b1off + m * 2048); \
            acc0[m] = __builtin_amdgcn_mfma_f32_16x16x32_bf16(a1, b01, acc0[m], 0, 0, 0); \
            acc1[m] = __builtin_amdgcn_mfma_f32_16x16x32_bf16(a1, b11, acc1[m], 0, 0, 0); } }

    float4 w0, w1, w2, w3, w4, w5, w6, w7;

    // prologue: W(0) then stage(0)  (FIFO: W older than stage)
    LOADW(w, kbase);
    MEMBAR;
    STAGE(0, kbase);
    MEMBAR;

    const int nph = kchunk / BK;
    int k0 = 0;
    for (int ph = 0; ph < nph; ++ph) {
        // pack W(t): implicit wait drains W(t) (oldest); stage(t) stays outstanding
        short8 b00 = pack8(w0, w1);
        short8 b01 = pack8(w2, w3);
        short8 b10 = pack8(w4, w5);
        short8 b11 = pack8(w6, w7);
        MEMBAR;
        int knext = kbase + ((k0 + BK) & kmask);   // wraps on last phase (dead prefetch)
        LOADW(w, knext);                           // W(t+1) into freed regs
        MEMBAR;
        STAGE(((ph + 1) & 1) * ABUF_BYTES, knext); // stage(t+1) into other buffer
        MEMBAR;
        // queue: [stage(t):sw, W(t+1):8, stage(t+1):sw] -> retire stage(t)
        if (sw == 7) asm volatile("s_waitcnt vmcnt(15)" ::: "memory");
        else         asm volatile("s_waitcnt vmcnt(14)" ::: "memory");
        asm volatile("s_barrier" ::: "memory");    // all waves' stage(t) done
        COMPUTE((ph & 1) * ABUF_BYTES, b00, b01, b10, b11);
        asm volatile("s_barrier" ::: "memory");    // all done reading buf(t)
        k0 += BK;
    }
#undef STAGE
#undef LOADW
#undef COMPUTE

    if (gridDim.z == 1) {
        const float badd0 = bias[ncol0];
        const float badd1 = bias[ncol1];
        if (mat < 2) {
            ushort* outb = (mat == 0) ? qb : kb;
            #pragma unroll
            for (int m = 0; m < MT; ++m)
                for (int r = 0; r < 4; ++r) {
                    int row = m * 16 + kgrp * 4 + r;   // C/D: col=lane&15, row=(lane>>4)*4+r
                    outb[(size_t)row * DD + ncol0] = f2bf(acc0[m][r] + badd0);
                    outb[(size_t)row * DD + ncol1] = f2bf(acc1[m][r] + badd1);
                }
        } else {
            #pragma unroll
            for (int m = 0; m < MT; ++m)
                for (int r = 0; r < 4; ++r) {
                    int row = m * 16 + kgrp * 4 + r;
                    vt[(size_t)ncol0 * KPV + row] = f2bf(acc0[m][r] + badd0);
                    vt[(size_t)ncol1 * KPV + row] = f2bf(acc1[m][r] + badd1);
                }
        }
    } else {
        float* pp = part + ((size_t)mat * gridDim.z + blockIdx.z) * ((size_t)MPAD * DD);
        #pragma unroll
        for (int m = 0; m < MT; ++m)
            for (int r = 0; r < 4; ++r) {
                int row = m * 16 + kgrp * 4 + r;
                pp[(size_t)row * DD + ncol0] = acc0[m][r];
                pp[(size_t)row * DD + ncol1] = acc1[m][r];
            }
    }
}

// ---------------- kernel 2b: reduce partials for q,k -> bf16 + bias
// grid (4, 208, 2), block 256. thread: 8 cols of one row.
__global__ __launch_bounds__(256) void cvt_qk(const float* __restrict__ part,
                                              const float* __restrict__ bq, const float* __restrict__ bk,
                                              ushort* __restrict__ qb, ushort* __restrict__ kb, int ks) {
    const int mat = blockIdx.z;
    const int row = blockIdx.y;
    const int col = blockIdx.x * 2048 + threadIdx.x * 8;
    const float* bias = mat ? bk : bq;
    float s[8];
    {
        const float4 b0 = *reinterpret_cast<const float4*>(bias + col);
        const float4 b1 = *reinterpret_cast<const float4*>(bias + col + 4);
        s[0]=b0.x; s[1]=b0.y; s[2]=b0.z; s[3]=b0.w; s[4]=b1.x; s[5]=b1.y; s[6]=b1.z; s[7]=b1.w;
    }
    const float* pm = part + (size_t)mat * ks * MPAD * DD + (size_t)row * DD + col;
    for (int p = 0; p < ks; ++p) {
        const float4 a0 = *reinterpret_cast<const float4*>(pm + (size_t)p * MPAD * DD);
        const float4 a1 = *reinterpret_cast<const float4*>(pm + (size_t)p * MPAD * DD + 4);
        s[0]+=a0.x; s[1]+=a0.y; s[2]+=a0.z; s[3]+=a0.w; s[4]+=a1.x; s[5]+=a1.y; s[6]+=a1.z; s[7]+=a1.w;
    }
    short8 o;
    for (int j = 0; j < 8; ++j) o[j] = f2bf(s[j]);
    ushort* outb = mat ? kb : qb;
    *reinterpret_cast<short8*>(outb + (size_t)row * DD + col) = o;
}

// ---------------- kernel 2c: reduce V partials + transpose -> vt bf16 [8192][256]
__global__ void vtrans_r(const float* __restrict__ pv, const float* __restrict__ bv,
                         ushort* __restrict__ vt, int ks) {
    __shared__ float lds[64][65];
    const int t  = threadIdx.x;
    const int n0 = blockIdx.x * 64;
    const int k0 = blockIdx.y * 64;
    #pragma unroll
    for (int r = 0; r < 16; ++r) {
        int kl = r * 4 + (t >> 6);
        int nl = t & 63;
        int k  = k0 + kl;
        float v = 0.f;
        if (k < NROW) {
            v = bv[n0 + nl];
            for (int p = 0; p < ks; ++p)
                v += pv[(size_t)p * MPAD * DD + (size_t)k * DD + n0 + nl];
        }
        lds[nl][kl] = v;
    }
    __syncthreads();
    int nl   = t >> 2;
    int koff = (t & 3) * 16;
    short8 o0, o1;
    for (int j = 0; j < 8; ++j) { o0[j] = f2bf(lds[nl][koff + j]); o1[j] = f2bf(lds[nl][koff + 8 + j]); }
    short8* dst = reinterpret_cast<short8*>(vt + (size_t)(n0 + nl) * KPV + k0 + koff);
    dst[0] = o0; dst[1] = o1;
}

// ---------------- kernel 4: s = q @ k^T  (f32 [208][208]); grid (13,13), 4-wave K-split
__global__ __launch_bounds__(256) void sgemm(const ushort* __restrict__ qb, const ushort* __restrict__ kb,
                                             float* __restrict__ sbuf) {
    const int bm = blockIdx.y, bn = blockIdx.x;
    const int lane  = threadIdx.x & 63;
    const int wave  = threadIdx.x >> 6;
    const int col16 = lane & 15, kgrp = lane >> 4;
    const ushort* ap = qb + (size_t)(bm * 16 + col16) * DD + kgrp * 8;
    const ushort* bp = kb + (size_t)(bn * 16 + col16) * DD + kgrp * 8;
    f32x4 acc;
    for (int r = 0; r < 4; ++r) acc[r] = 0.f;
    const int kend = (wave + 1) * 2048;
    for (int k0 = wave * 2048; k0 < kend; k0 += 32) {
        short8 a = *reinterpret_cast<const short8*>(ap + k0);
        short8 b = *reinterpret_cast<const short8*>(bp + k0);
        acc = __builtin_amdgcn_mfma_f32_16x16x32_bf16(a, b, acc, 0, 0, 0);
    }
    __shared__ f32x4 red[4][64];
    red[wave][lane] = acc;
    __syncthreads();
    if (wave == 0) {
        f32x4 s = red[0][lane];
        for (int j = 1; j < 4; ++j) { f32x4 o = red[j][lane]; for (int r = 0; r < 4; ++r) s[r] += o[r]; }
        for (int r = 0; r < 4; ++r)
            sbuf[(size_t)(bm * 16 + kgrp * 4 + r) * MPAD + bn * 16 + col16] = s[r];
    }
}

// ---------------- kernel 5: per-row mean/var(ddof=1) -> sin -> softmax -> P bf16 [208][256] (pads 0)
__global__ __launch_bounds__(256) void rownorm(const float* __restrict__ sbuf, ushort* __restrict__ pb) {
    const int row = blockIdx.x;
    const int t = threadIdx.x;
    if (row >= NROW) { pb[(size_t)row * KPV + t] = 0; return; }
    __shared__ float part[4];
    const int lane = t & 63, wave = t >> 6;
    float x = (t < NROW) ? sbuf[(size_t)row * MPAD + t] : 0.f;

    float s = x;
    for (int m = 32; m; m >>= 1) s += __shfl_xor(s, m, 64);
    if (lane == 0) part[wave] = s;
    __syncthreads();
    float mean = (part[0] + part[1] + part[2] + part[3]) * (1.f / 200.f);

    float d = (t < NROW) ? (x - mean) : 0.f;
    float s2 = d * d;
    for (int m = 32; m; m >>= 1) s2 += __shfl_xor(s2, m, 64);
    __syncthreads();
    if (lane == 0) part[wave] = s2;
    __syncthreads();
    float var = (part[0] + part[1] + part[2] + part[3]) * (1.f / 199.f);

    float inv = 1.f / sqrtf(var + EPSV);
    float y = sinf(d * inv);
    const float inv_cc = 1.f / 90.50966799187809f;   // 1/sqrt(8192)
    float e = (t < NROW) ? expf(y * inv_cc) : 0.f;

    float se = e;
    for (int m = 32; m; m >>= 1) se += __shfl_xor(se, m, 64);
    __syncthreads();
    if (lane == 0) part[wave] = se;
    __syncthreads();
    float tot = part[0] + part[1] + part[2] + part[3];
    pb[(size_t)row * KPV + t] = (t < NROW) ? f2bf(e / tot) : (ushort)0;
}

// ---------------- kernel 6: out = P @ V  via out[m][n] = sum_k P[m][k] * vt[n][k]
__global__ __launch_bounds__(256) void pv_gemm(const ushort* __restrict__ pb, const ushort* __restrict__ vt,
                                               float* __restrict__ out) {
    const int lane  = threadIdx.x & 63;
    const int wave  = threadIdx.x >> 6;
    const int col16 = lane & 15, kgrp = lane >> 4;
    const int ncol  = blockIdx.x * 64 + wave * 16 + col16;
    const ushort* ap = pb + (size_t)col16 * KPV + kgrp * 8;
    const ushort* bp = vt + (size_t)ncol  * KPV + kgrp * 8;
    f32x4 acc[MT];
    for (int m = 0; m < MT; ++m)
        for (int r = 0; r < 4; ++r) acc[m][r] = 0.f;
    for (int k0 = 0; k0 < KPV; k0 += 32) {
        short8 b = *reinterpret_cast<const short8*>(bp + k0);
        #pragma unroll
        for (int m = 0; m < MT; ++m) {
            short8 a = *reinterpret_cast<const short8*>(ap + (size_t)m * 16 * KPV + k0);
            acc[m] = __builtin_amdgcn_mfma_f32_16x16x32_bf16(a, b, acc[m], 0, 0, 0);
        }
    }
    for (int m = 0; m < MT; ++m)
        for (int r = 0; r < 4; ++r) {
            int row = m * 16 + kgrp * 4 + r;
            if (row < NROW) out[(size_t)row * DD + ncol] = acc[m][r];
        }
}

extern "C" void kernel_launch(void* const* d_in, const int* in_sizes, int n_in,
                              void* d_out, int out_size, void* d_ws, size_t ws_size,
                              hipStream_t stream) {
    const float* x  = (const float*)d_in[0];
    const float* Wq = (const float*)d_in[1];
    const float* bq = (const float*)d_in[2];
    const float* Wk = (const float*)d_in[3];
    const float* bk = (const float*)d_in[4];
    const float* Wv = (const float*)d_in[5];
    const float* bv = (const float*)d_in[6];
    float* out = (float*)d_out;

    char* ws = (char*)d_ws;
    ushort* xb   = (ushort*)(ws);                       // 208*8192*2 = 3,407,872
    ushort* qb   = (ushort*)(ws + 3407872);             // 3,407,872
    ushort* kb   = (ushort*)(ws + 6815744);             // 3,407,872
    ushort* vt   = (ushort*)(ws + 10223616);            // 8192*256*2 = 4,194,304
    float*  sbuf = (float*)(ws + 14417920);             // 208*208*4 = 173,056
    ushort* pb   = (ushort*)(ws + 14590976);            // 208*256*2 = 106,496
    float*  part = (float*)(ws + 14697472);             // 3*4*208*8192*4 = 81,788,928

    const size_t need4 = 14697472u + (size_t)3 * 4 * MPAD * DD * 4;  // 96,486,400
    const int ks = (ws_size >= need4) ? 4 : 1;

    cvt_x<<<832, 256, 0, stream>>>(x, xb);
    if (ks == 4) {
        qkv_gemm<<<dim3(64, 3, 4), 256, 0, stream>>>(xb, Wq, Wk, Wv, bq, bk, bv,
                                                     qb, kb, vt, part, DD / 4);
        cvt_qk<<<dim3(4, MPAD, 2), 256, 0, stream>>>(part, bq, bk, qb, kb, 4);
        vtrans_r<<<dim3(128, 4), 256, 0, stream>>>(part + (size_t)2 * 4 * MPAD * DD, bv, vt, 4);
    } else {
        qkv_gemm<<<dim3(64, 3, 1), 256, 0, stream>>>(xb, Wq, Wk, Wv, bq, bk, bv,
                                                     qb, kb, vt, part, DD);
    }
    sgemm<<<dim3(13, 13), 256, 0, stream>>>(qb, kb, sbuf);
    rownorm<<<208, 256, 0, stream>>>(sbuf, pb);
    pv_gemm<<<128, 256, 0, stream>>>(pb, vt, out);
}

// Round 7
// 378.496 us; speedup vs baseline: 1.1153x; 1.1153x over previous
//
#include <hip/hip_runtime.h>
#include <hip/hip_bf16.h>
#include <cstdint>

#define DD 8192
#define NROW 200
#define MT 13          // 13 M-tiles of 16 rows = 208
#define MPAD 208
#define KPV 256        // padded K for the PV GEMM
#define EPSV 1e-5f
#define BK32 32
#define ABUF 13312     // 208*32*2 bytes per A LDS buffer
#define WBUF 2048      // 32*32*2  bytes per W LDS buffer (bf16)
#define LDSTOT (2*ABUF + 2*WBUF)   // 30720 -> 3 blocks/CU

using short8 = __attribute__((ext_vector_type(8))) short;
using f32x4  = __attribute__((ext_vector_type(4))) float;

#define MEMBAR asm volatile("" ::: "memory")

__device__ __forceinline__ ushort f2bf(float f) {
    union { float f; unsigned u; } c; c.f = f;
    unsigned u = c.u;
    return (ushort)((u + 0x7FFFu + ((u >> 16) & 1u)) >> 16);  // RNE
}

__device__ __forceinline__ short8 pack8(float4 a, float4 b) {
    short8 o;
    o[0]=f2bf(a.x); o[1]=f2bf(a.y); o[2]=f2bf(a.z); o[3]=f2bf(a.w);
    o[4]=f2bf(b.x); o[5]=f2bf(b.y); o[6]=f2bf(b.z); o[7]=f2bf(b.w);
    return o;
}

// ---------------- kernel 1: x (f32 [200][8192]) -> xb (bf16 [208][8192], pad rows 0)
__global__ void cvt_x(const float* __restrict__ x, ushort* __restrict__ xb) {
    int i = (blockIdx.x * 256 + threadIdx.x) * 8;
    int row = i >> 13;
    int col = i & (DD - 1);
    short8 o;
    if (row < NROW) {
        const float4* p = reinterpret_cast<const float4*>(x + (size_t)row * DD + col);
        float4 a = p[0], b = p[1];
        o = pack8(a, b);
    } else {
        for (int j = 0; j < 8; ++j) o[j] = 0;
    }
    *reinterpret_cast<short8*>(xb + i) = o;
}

// ---------------- kernel 2: fused QKV GEMM, M-split waves, W via LDS.
// grid (256, 3), block 256 (4 waves). Block: 32 N-cols x 208 rows x full K.
// Wave w owns M-tiles {w, w+4, w+8, w+12} (tiles >=13 computed dead, not stored).
// A k-slice [208][32] bf16 dbuf via global_load_lds (chunk-XOR swizzled source);
// W k-slice [32][32] staged fp32->bf16 by all threads (T14: load early, ds_write late).
// 3 blocks/CU = 12 waves/CU. Counted vmcnt, raw barriers (2/phase).
__global__ __launch_bounds__(256, 3) void qkv_ms(
    const ushort* __restrict__ xb,
    const float* __restrict__ Wq, const float* __restrict__ Wk, const float* __restrict__ Wv,
    const float* __restrict__ bq, const float* __restrict__ bk, const float* __restrict__ bv,
    ushort* __restrict__ qb, ushort* __restrict__ kb, ushort* __restrict__ vt)
{
    __shared__ char L[LDSTOT];   // [A0:13312][A1:13312][W0:2048][W1:2048]

    const int mat = blockIdx.y;
    const float* W    = (mat == 0) ? Wq : (mat == 1 ? Wk : Wv);
    const float* bias = (mat == 0) ? bq : (mat == 1 ? bk : bv);

    const int t    = threadIdx.x;
    const int lane = t & 63;
    const int wave = t >> 6;
    const int c    = lane & 15;
    const int kgrp = lane >> 4;
    const int ncol0 = blockIdx.x * 32 + c;
    const int ncol1 = ncol0 + 16;

    // ---- A staging: round r covers rows r*64..r*64+63 (round 3: rows 192-207, wave 0 only).
    // LDS linear [row][4 x 16B chunk-pos]; content k-chunk = pos ^ ((row>>1)&3).
    const ushort* sA = xb + (size_t)(t >> 2) * DD + (size_t)(((t & 3) ^ ((t >> 3) & 3)) * 8);
    // ---- W staging: thread t loads W[col=t>>3][k: (t&7)*4..+4] fp32, packs, writes swizzled.
    const float* sW = W + (size_t)(blockIdx.x * 32 + (t >> 3)) * DD + (t & 7) * 4;
    const int wdst = (t >> 3) * 64 + ((((t & 7) >> 1) ^ ((t >> 4) & 3)) * 16) + (t & 1) * 8;

    // ---- reads: rows are 64B; swizzled chunk-pos p = kgrp ^ ((c>>1)&3) (same for A & W)
    const int p    = kgrp ^ ((c >> 1) & 3);
    const int roff = c * 64 + p * 16;

    f32x4 acc0[4], acc1[4];
    #pragma unroll
    for (int j = 0; j < 4; ++j)
        for (int r = 0; r < 4; ++r) { acc0[j][r] = 0.f; acc1[j][r] = 0.f; }

#define STAGE_A(DST, KK) { \
        __builtin_amdgcn_global_load_lds((const __attribute__((address_space(1))) void*)(sA + (KK)), \
            (__attribute__((address_space(3))) void*)(L + (DST) + wave * 1024), 16, 0, 0); \
        __builtin_amdgcn_global_load_lds((const __attribute__((address_space(1))) void*)(sA + (KK) + 64 * DD), \
            (__attribute__((address_space(3))) void*)(L + (DST) + 4096 + wave * 1024), 16, 0, 0); \
        __builtin_amdgcn_global_load_lds((const __attribute__((address_space(1))) void*)(sA + (KK) + 128 * DD), \
            (__attribute__((address_space(3))) void*)(L + (DST) + 8192 + wave * 1024), 16, 0, 0); \
        if (wave == 0) { \
            __builtin_amdgcn_global_load_lds((const __attribute__((address_space(1))) void*)(sA + (KK) + 192 * DD), \
                (__attribute__((address_space(3))) void*)(L + (DST) + 12288), 16, 0, 0); } }

#define WRITE_W(WD, wreg) { \
        uint2 pw; \
        pw.x = (unsigned)f2bf(wreg.x) | ((unsigned)f2bf(wreg.y) << 16); \
        pw.y = (unsigned)f2bf(wreg.z) | ((unsigned)f2bf(wreg.w) << 16); \
        *reinterpret_cast<uint2*>(L + (WD) + wdst) = pw; }

    // ---------------- prologue: W(0) load, A(0) stage -> buf0, W(0) -> Wbuf0
    float4 wreg = *reinterpret_cast<const float4*>(sW);
    MEMBAR;
    STAGE_A(0, 0);
    MEMBAR;
    if (wave == 0) asm volatile("s_waitcnt vmcnt(4)" ::: "memory");
    else           asm volatile("s_waitcnt vmcnt(3)" ::: "memory");
    WRITE_W(2 * ABUF, wreg);
    asm volatile("s_waitcnt lgkmcnt(0)" ::: "memory");

    int kk = 0;
    for (int ph = 0; ph < DD / BK32; ++ph) {
        const int cur = ph & 1;
        const int knext = (kk + BK32) & (DD - 1);   // wraps on last phase (dead prefetch)

        // early: issue W(t+1) global load, then A(t+1) stage
        wreg = *reinterpret_cast<const float4*>(sW + knext);
        MEMBAR;
        STAGE_A((cur ^ 1) * ABUF, knext);
        MEMBAR;

        // retire A(t); barrier; compute
        if (wave == 0) asm volatile("s_waitcnt vmcnt(5)" ::: "memory");
        else           asm volatile("s_waitcnt vmcnt(4)" ::: "memory");
        asm volatile("s_barrier" ::: "memory");

        {
            const char* Ab = L + cur * ABUF;
            const char* Wb = L + 2 * ABUF + cur * WBUF;
            short8 b0 = *reinterpret_cast<const short8*>(Wb + roff);
            short8 b1 = *reinterpret_cast<const short8*>(Wb + 1024 + roff);
            #pragma unroll
            for (int j = 0; j < 4; ++j) {
                short8 a = *reinterpret_cast<const short8*>(Ab + (wave + 4 * j) * 1024 + roff);
                acc0[j] = __builtin_amdgcn_mfma_f32_16x16x32_bf16(a, b0, acc0[j], 0, 0, 0);
                acc1[j] = __builtin_amdgcn_mfma_f32_16x16x32_bf16(a, b1, acc1[j], 0, 0, 0);
            }
        }
        __builtin_amdgcn_sched_barrier(0);

        // late: W(t+1) -> LDS (needs its global load done; A(t+1) stays in flight)
        if (wave == 0) asm volatile("s_waitcnt vmcnt(4)" ::: "memory");
        else           asm volatile("s_waitcnt vmcnt(3)" ::: "memory");
        WRITE_W(2 * ABUF + (cur ^ 1) * WBUF, wreg);
        asm volatile("s_waitcnt lgkmcnt(0)" ::: "memory");
        asm volatile("s_barrier" ::: "memory");

        kk += BK32;
    }
#undef STAGE_A
#undef WRITE_W

    // ---------------- epilogue
    const float b0v = bias[ncol0];
    const float b1v = bias[ncol1];
    if (mat < 2) {
        ushort* outb = (mat == 0) ? qb : kb;
        #pragma unroll
        for (int j = 0; j < 4; ++j) {
            int mt = wave + 4 * j;
            if (mt < MT) {
                #pragma unroll
                for (int r = 0; r < 4; ++r) {
                    int row = mt * 16 + kgrp * 4 + r;   // C/D: col=lane&15, row=(lane>>4)*4+r
                    outb[(size_t)row * DD + ncol0] = f2bf(acc0[j][r] + b0v);
                    outb[(size_t)row * DD + ncol1] = f2bf(acc1[j][r] + b1v);
                }
            }
        }
    } else {
        #pragma unroll
        for (int j = 0; j < 4; ++j) {
            int mt = wave + 4 * j;
            if (mt < MT) {
                #pragma unroll
                for (int r = 0; r < 4; ++r) {
                    int row = mt * 16 + kgrp * 4 + r;
                    vt[(size_t)ncol0 * KPV + row] = f2bf(acc0[j][r] + b0v);
                    vt[(size_t)ncol1 * KPV + row] = f2bf(acc1[j][r] + b1v);
                }
            }
        }
    }
}

// ---------------- kernel 4: s = q @ k^T  (f32 [208][208]); grid (13,13), 4-wave K-split
__global__ __launch_bounds__(256) void sgemm(const ushort* __restrict__ qb, const ushort* __restrict__ kb,
                                             float* __restrict__ sbuf) {
    const int bm = blockIdx.y, bn = blockIdx.x;
    const int lane  = threadIdx.x & 63;
    const int wave  = threadIdx.x >> 6;
    const int col16 = lane & 15, kgrp = lane >> 4;
    const ushort* ap = qb + (size_t)(bm * 16 + col16) * DD + kgrp * 8;
    const ushort* bp = kb + (size_t)(bn * 16 + col16) * DD + kgrp * 8;
    f32x4 acc;
    for (int r = 0; r < 4; ++r) acc[r] = 0.f;
    const int kend = (wave + 1) * 2048;
    for (int k0 = wave * 2048; k0 < kend; k0 += 32) {
        short8 a = *reinterpret_cast<const short8*>(ap + k0);
        short8 b = *reinterpret_cast<const short8*>(bp + k0);
        acc = __builtin_amdgcn_mfma_f32_16x16x32_bf16(a, b, acc, 0, 0, 0);
    }
    __shared__ f32x4 red[4][64];
    red[wave][lane] = acc;
    __syncthreads();
    if (wave == 0) {
        f32x4 s = red[0][lane];
        for (int j = 1; j < 4; ++j) { f32x4 o = red[j][lane]; for (int r = 0; r < 4; ++r) s[r] += o[r]; }
        for (int r = 0; r < 4; ++r)
            sbuf[(size_t)(bm * 16 + kgrp * 4 + r) * MPAD + bn * 16 + col16] = s[r];
    }
}

// ---------------- kernel 5: per-row mean/var(ddof=1) -> sin -> softmax -> P bf16 [208][256] (pads 0)
__global__ __launch_bounds__(256) void rownorm(const float* __restrict__ sbuf, ushort* __restrict__ pb) {
    const int row = blockIdx.x;
    const int t = threadIdx.x;
    if (row >= NROW) { pb[(size_t)row * KPV + t] = 0; return; }
    __shared__ float part[4];
    const int lane = t & 63, wave = t >> 6;
    float x = (t < NROW) ? sbuf[(size_t)row * MPAD + t] : 0.f;

    float s = x;
    for (int m = 32; m; m >>= 1) s += __shfl_xor(s, m, 64);
    if (lane == 0) part[wave] = s;
    __syncthreads();
    float mean = (part[0] + part[1] + part[2] + part[3]) * (1.f / 200.f);

    float d = (t < NROW) ? (x - mean) : 0.f;
    float s2 = d * d;
    for (int m = 32; m; m >>= 1) s2 += __shfl_xor(s2, m, 64);
    __syncthreads();
    if (lane == 0) part[wave] = s2;
    __syncthreads();
    float var = (part[0] + part[1] + part[2] + part[3]) * (1.f / 199.f);

    float inv = 1.f / sqrtf(var + EPSV);
    float y = sinf(d * inv);
    const float inv_cc = 1.f / 90.50966799187809f;   // 1/sqrt(8192)
    float e = (t < NROW) ? expf(y * inv_cc) : 0.f;

    float se = e;
    for (int m = 32; m; m >>= 1) se += __shfl_xor(se, m, 64);
    __syncthreads();
    if (lane == 0) part[wave] = se;
    __syncthreads();
    float tot = part[0] + part[1] + part[2] + part[3];
    pb[(size_t)row * KPV + t] = (t < NROW) ? f2bf(e / tot) : (ushort)0;
}

// ---------------- kernel 6: out = P @ V  via out[m][n] = sum_k P[m][k] * vt[n][k]
__global__ __launch_bounds__(256) void pv_gemm(const ushort* __restrict__ pb, const ushort* __restrict__ vt,
                                               float* __restrict__ out) {
    const int lane  = threadIdx.x & 63;
    const int wave  = threadIdx.x >> 6;
    const int col16 = lane & 15, kgrp = lane >> 4;
    const int ncol  = blockIdx.x * 64 + wave * 16 + col16;
    const ushort* ap = pb + (size_t)col16 * KPV + kgrp * 8;
    const ushort* bp = vt + (size_t)ncol  * KPV + kgrp * 8;
    f32x4 acc[MT];
    for (int m = 0; m < MT; ++m)
        for (int r = 0; r < 4; ++r) acc[m][r] = 0.f;
    for (int k0 = 0; k0 < KPV; k0 += 32) {
        short8 b = *reinterpret_cast<const short8*>(bp + k0);
        #pragma unroll
        for (int m = 0; m < MT; ++m) {
            short8 a = *reinterpret_cast<const short8*>(ap + (size_t)m * 16 * KPV + k0);
            acc[m] = __builtin_amdgcn_mfma_f32_16x16x32_bf16(a, b, acc[m], 0, 0, 0);
        }
    }
    for (int m = 0; m < MT; ++m)
        for (int r = 0; r < 4; ++r) {
            int row = m * 16 + kgrp * 4 + r;
            if (row < NROW) out[(size_t)row * DD + ncol] = acc[m][r];
        }
}

extern "C" void kernel_launch(void* const* d_in, const int* in_sizes, int n_in,
                              void* d_out, int out_size, void* d_ws, size_t ws_size,
                              hipStream_t stream) {
    const float* x  = (const float*)d_in[0];
    const float* Wq = (const float*)d_in[1];
    const float* bq = (const float*)d_in[2];
    const float* Wk = (const float*)d_in[3];
    const float* bk = (const float*)d_in[4];
    const float* Wv = (const float*)d_in[5];
    const float* bv = (const float*)d_in[6];
    float* out = (float*)d_out;

    char* ws = (char*)d_ws;
    ushort* xb   = (ushort*)(ws);                       // 208*8192*2 = 3,407,872
    ushort* qb   = (ushort*)(ws + 3407872);             // 3,407,872
    ushort* kb   = (ushort*)(ws + 6815744);             // 3,407,872
    ushort* vt   = (ushort*)(ws + 10223616);            // 8192*256*2 = 4,194,304
    float*  sbuf = (float*)(ws + 14417920);             // 208*208*4 = 173,056
    ushort* pb   = (ushort*)(ws + 14590976);            // 208*256*2 = 106,496
    // total 14,697,472 bytes

    cvt_x<<<832, 256, 0, stream>>>(x, xb);
    qkv_ms<<<dim3(256, 3), 256, 0, stream>>>(xb, Wq, Wk, Wv, bq, bk, bv, qb, kb, vt);
    sgemm<<<dim3(13, 13), 256, 0, stream>>>(qb, kb, sbuf);
    rownorm<<<208, 256, 0, stream>>>(sbuf, pb);
    pv_gemm<<<128, 256, 0, stream>>>(pb, vt, out);
}